// Round 20
// baseline (144.957 us; speedup 1.0000x reference)
//
#include <hip/hip_runtime.h>

#define NB 2
#define LX 2048
#define LZ 2048
#define HH 16
#define DA 64
#define DM 64
#define HD 1024
#define MINF  -1000000.0f
#define QSC   0.1803368801f   // 0.125 * log2(e): softmax done in base-2 domain
#define DTHR  8.0f            // defer-max threshold (base-2): P <= 2^8

typedef __attribute__((ext_vector_type(8))) short short8;
typedef __attribute__((ext_vector_type(4))) float f32x4;

static __device__ __forceinline__ ushort f2bf(float f) {
    union { float f; uint32_t u; } c; c.f = f;
    return (ushort)((c.u + 0x7FFFu + ((c.u >> 16) & 1u)) >> 16);
}

static __device__ __forceinline__ float bf2f(ushort u) {
    union { uint32_t u; float f; } c; c.u = (uint32_t)u << 16;
    return c.f;
}

static __device__ __forceinline__ uint32_t cvtpk(float lo, float hi) {
    uint32_t r;
    asm("v_cvt_pk_bf16_f32 %0, %1, %2" : "=v"(r) : "v"(lo), "v"(hi));
    return r;
}

#define GL16(g, l) __builtin_amdgcn_global_load_lds( \
    (const __attribute__((address_space(1))) void*)(g), \
    (__attribute__((address_space(3))) void*)(l), 16, 0, 0)

// ---------------------------------------------------------------------------
// Fused preprocessing, one launch (11264 blocks):
//   [0,8192)      fp32->bf16 of both activations
//   [8192,9216)   4 weight transposes (f32 [K][N] -> bf16 [N][K])
//   [9216,11264)  mask tile classification (0 all-masked / 1 all-pass / 2 mix)
// ---------------------------------------------------------------------------
__global__ __launch_bounds__(256) void prep(
    const float* __restrict__ pA, const float* __restrict__ pB,
    ushort* __restrict__ oA, ushort* __restrict__ oB,
    const float* __restrict__ W0, const float* __restrict__ W1,
    const float* __restrict__ W2, const float* __restrict__ W3,
    ushort* __restrict__ T0, ushort* __restrict__ T1,
    ushort* __restrict__ T2, ushort* __restrict__ T3,
    const int* __restrict__ amask, const int* __restrict__ pmask,
    int* __restrict__ cls)
{
    const int fid = blockIdx.x;
    const int t = threadIdx.x;
    if (fid < 8192) {
        const int i = fid * 256 + t;
        const float* in = (i < 1048576) ? pA : pB;
        ushort* out = (i < 1048576) ? oA : oB;
        const int j = i & 1048575;
        float4 v = ((const float4*)in)[j];
        ushort4 o;
        o.x = f2bf(v.x); o.y = f2bf(v.y); o.z = f2bf(v.z); o.w = f2bf(v.w);
        ((ushort4*)out)[j] = o;
    } else if (fid < 9216) {
        __shared__ ushort Ls[64][72];
        const int id2 = fid - 8192;                 // 0..1023
        const int zz = id2 >> 8, rem = id2 & 255;
        const float* W = (zz == 0) ? W0 : (zz == 1) ? W1 : (zz == 2) ? W2 : W3;
        ushort* Wt = (zz == 0) ? T0 : (zz == 1) ? T1 : (zz == 2) ? T2 : T3;
        const int n0 = (rem & 15) * 64, k0 = (rem >> 4) * 64;
        const int rr = t >> 4, c4 = (t & 15) * 4;
        #pragma unroll
        for (int i = 0; i < 4; ++i) {
            const int r = rr + i * 16;
            float4 v = *(const float4*)&W[(size_t)(k0 + r) * 1024 + n0 + c4];
            Ls[c4 + 0][r] = f2bf(v.x);
            Ls[c4 + 1][r] = f2bf(v.y);
            Ls[c4 + 2][r] = f2bf(v.z);
            Ls[c4 + 3][r] = f2bf(v.w);
        }
        __syncthreads();
        const int n = t >> 2, kc = (t & 3) * 16;
        *(short8*)&Wt[(size_t)(n0 + n) * 1024 + k0 + kc]     = *(const short8*)&Ls[n][kc];
        *(short8*)&Wt[(size_t)(n0 + n) * 1024 + k0 + kc + 8] = *(const short8*)&Ls[n][kc + 8];
    } else {
        const int bid = fid - 9216;                 // 0..2047
        const int b = bid >> 10, xb = (bid >> 5) & 31, zb = bid & 31;
        int andv = 1, orv = 0;
        #pragma unroll
        for (int i = 0; i < 16; ++i) {
            const int e = t + i * 256;
            const int r = e >> 6, z = e & 63;
            const int m = amask[((size_t)b * LX + xb * 64 + r) * LZ + zb * 64 + z];
            const int p = pmask[(size_t)b * LZ + zb * 64 + z];
            const int v = (m != 0) & (p != 0);
            andv &= v; orv |= v;
        }
        __shared__ int sa[256];
        __shared__ int so[256];
        sa[t] = andv; so[t] = orv;
        __syncthreads();
        for (int s = 128; s > 0; s >>= 1) {
            if (t < s) { sa[t] &= sa[t + s]; so[t] |= so[t + s]; }
            __syncthreads();
        }
        if (t == 0) cls[bid] = so[0] ? (sa[0] ? 1 : 2) : 0;
    }
}

// ---------------------------------------------------------------------------
// Fused Q + K + V projection GEMM (m97 structure, 128x128 tile, BK=32,
// 768 blocks = 3/CU). bx<8: Q (x QSC) -> Qb[4096][1024]. bx 8..15: K ->
// Kb[4096][1024]. bx>=16: V, stored TRANSPOSED via LDS epilogue ->
// VT[1024 vcols][4096 z] so attention can GL16-stage V tiles (contiguous z).
// (r15-verified epilogue; r15's failure was attn-side per-frag gather.)
// ---------------------------------------------------------------------------
__global__ __launch_bounds__(256) void gemm_qkv(
    const ushort* __restrict__ Pb, const ushort* __restrict__ Cb,
    const ushort* __restrict__ Wqt, const ushort* __restrict__ Wkvt,
    ushort* __restrict__ Qb, ushort* __restrict__ Kb, ushort* __restrict__ VT)
{
    __shared__ ushort sh[8704];        // As(4096)+Bs(4096); epilogue Ls(8704)
    ushort* As = sh;
    ushort* Bs = sh + 4096;

    const int bx = blockIdx.x;
    const bool isQ = bx < 8;
    const bool isV = bx >= 16;
    const ushort* A  = isQ ? Pb : Cb;
    const ushort* Bt = isQ ? Wqt : Wkvt;
    const int n0 = (isQ ? bx : bx - 8) * 128;   // col in Wqt / Wkvt (0..2047)
    const float osc = isQ ? QSC : 1.0f;

    const int t = threadIdx.x;
    const int w = t >> 6, l = t & 63, lr = l & 15, lg = l >> 4;
    const int wr = w >> 1, wc = w & 1;
    const int m0 = blockIdx.y * 128;

    const int c0 = t, c1 = t + 256;
    const ushort* a0 = &A[(size_t)(m0 + (c0 >> 2)) * 1024 + (c0 & 3) * 8];
    const ushort* a1 = &A[(size_t)(m0 + (c1 >> 2)) * 1024 + (c1 & 3) * 8];
    const ushort* b0 = &Bt[(size_t)(n0 + (c0 >> 2)) * 1024 + (c0 & 3) * 8];
    const ushort* b1 = &Bt[(size_t)(n0 + (c1 >> 2)) * 1024 + (c1 & 3) * 8];
    ushort* lA0 = &As[w * 512];
    ushort* lA1 = &As[(4 + w) * 512];
    ushort* lB0 = &Bs[w * 512];
    ushort* lB1 = &Bs[(4 + w) * 512];

    f32x4 acc[4][4];
    #pragma unroll
    for (int i = 0; i < 4; ++i)
        #pragma unroll
        for (int j = 0; j < 4; ++j) acc[i][j] = 0.f;

    for (int k0 = 0; k0 < 1024; k0 += 32) {
        __syncthreads();
        GL16(a0 + k0, lA0);
        GL16(a1 + k0, lA1);
        GL16(b0 + k0, lB0);
        GL16(b1 + k0, lB1);
        __syncthreads();
        short8 af[4], bf[4];
        #pragma unroll
        for (int mi = 0; mi < 4; ++mi)
            af[mi] = *(const short8*)&As[(wr * 64 + mi * 16 + lr) * 32 + lg * 8];
        #pragma unroll
        for (int nj = 0; nj < 4; ++nj)
            bf[nj] = *(const short8*)&Bs[(wc * 64 + nj * 16 + lr) * 32 + lg * 8];
        #pragma unroll
        for (int mi = 0; mi < 4; ++mi)
            #pragma unroll
            for (int nj = 0; nj < 4; ++nj)
                acc[mi][nj] = __builtin_amdgcn_mfma_f32_16x16x32_bf16(
                    af[mi], bf[nj], acc[mi][nj], 0, 0, 0);
    }

    if (!isV) {
        ushort* Cout = isQ ? Qb : Kb;
        const int row0 = m0 + wr * 64, col0 = n0 + wc * 64;
        #pragma unroll
        for (int mi = 0; mi < 4; ++mi)
            #pragma unroll
            for (int nj = 0; nj < 4; ++nj) {
                const int col = col0 + nj * 16 + lr;
                #pragma unroll
                for (int r = 0; r < 4; ++r) {
                    const int row = row0 + mi * 16 + lg * 4 + r;
                    Cout[(size_t)row * 1024 + col] = f2bf(acc[mi][nj][r] * osc);
                }
            }
    } else {
        // transpose-store V: acc rows = z (m0..m0+127), cols = vcol.
        // Two 64-vcol halves through LDS Ls[64][136].
        #pragma unroll
        for (int h2 = 0; h2 < 2; ++h2) {
            __syncthreads();
            if (wc == h2) {
                #pragma unroll
                for (int nj = 0; nj < 4; ++nj)
                    #pragma unroll
                    for (int mi = 0; mi < 4; ++mi)
                        #pragma unroll
                        for (int r = 0; r < 4; ++r)
                            sh[(nj * 16 + lr) * 136 + wr * 64 + mi * 16 + lg * 4 + r]
                                = f2bf(acc[mi][nj][r]);
            }
            __syncthreads();
            const int vcl = t >> 2, seg = t & 3;
            const int vcol = (n0 - 1024) + h2 * 64 + vcl;
            ushort* dst = &VT[(size_t)vcol * 4096 + m0 + seg * 32];
            const ushort* srcl = &sh[vcl * 136 + seg * 32];
            *(short8*)(dst + 0)  = *(const short8*)(srcl + 0);
            *(short8*)(dst + 8)  = *(const short8*)(srcl + 8);
            *(short8*)(dst + 16) = *(const short8*)(srcl + 16);
            *(short8*)(dst + 24) = *(const short8*)(srcl + 24);
        }
    }
}

// ---------------------------------------------------------------------------
// MFMA flash attention, qb-paired stage-once-compute-twice (r19) with
// FULLY GL16 staging (zero staging VALU):
//  - K from Kb via GL16, per-lane global source pre-XOR'd (chunk ^= z&7),
//    linear Ks[64][64]; frag reads apply same XOR -> 0 bank conflicts (r16).
//  - V from producer-transposed VT via GL16, source chunk pre-XOR'd by
//    f(m) = (m^(m>>3))&7 -> reproduces the chunk-XOR Vt layout byte-for-byte;
//    PV reads UNCHANGED (conflict-free). V-pack loop + ds_writes deleted.
// Split-KV x2, 1024 uniform paired blocks, balanced XCD clustering, swapped
// QK^T, zero-shuffle PV (sigma z-order), defer-max, deferred l-reduction,
// setprio(1) on MFMA. Writes PARTIAL O (bf16) + (m,l) f32.
// ---------------------------------------------------------------------------
__global__ __launch_bounds__(256, 4) void attn_mfma(
    const ushort* __restrict__ Qg, const ushort* __restrict__ Kb,
    const ushort* __restrict__ VTg, const int* __restrict__ amask,
    const int* __restrict__ pmask, const int* __restrict__ cls,
    ushort* __restrict__ Op, float2* __restrict__ ml)
{
    __shared__ ushort Ks[64 * 64];   // [z][d-chunk swizzled], linear for GL16
    __shared__ ushort Vt[64 * 64];   // [m][z-chunk swizzled], linear for GL16

    const int t = threadIdx.x, w = t >> 6, l = t & 63, lr = l & 15, lg = l >> 4;
    // balanced XCD clustering over 1024 blocks: XCD x gets groups {x,x+8,..}
    const int flat = blockIdx.x + 16 * (blockIdx.y + 16 * blockIdx.z); // 0..1023
    const int xcd = flat & 7, ii = flat >> 3;       // ii 0..127
    const int g = xcd + 8 * (ii >> 4);              // 0..63 (h,bs) group
    const int pp = ii & 15;                         // pair index 0..15
    const int h = g & 15, bs = g >> 4;              // bs 0..3
    const int b = bs & 1, sKV = bs >> 1;
    const uint32_t halfm = sKV ? 0xAAAAAAAAu : 0x55555555u;

    // per-strip setup (statically indexed throughout)
    const int qb0 = pp, qb1 = 31 - pp;
    const int qw0 = qb0 * 64 + w * 16, qw1 = qb1 * 64 + w * 16;
    const int cv0 = cls[b * 1024 + qb0 * 32 + (l & 31)];
    const int cv1 = cls[b * 1024 + qb1 * 32 + (l & 31)];
    const uint32_t act0 = (uint32_t)__ballot(cv0 != 0) & halfm;
    const uint32_t mix0 = (uint32_t)__ballot(cv0 == 2) & halfm;
    const uint32_t act1 = (uint32_t)__ballot(cv1 != 0) & halfm;
    const uint32_t mix1 = (uint32_t)__ballot(cv1 == 2) & halfm;

    // Q B-frags per strip: lane holds Q[q = lr][d = ks*32 + lg*8 .. +8]
    short8 qfA[2], qfB[2];
    #pragma unroll
    for (int ks = 0; ks < 2; ++ks) {
        qfA[ks] = *(const short8*)&Qg[(size_t)(b * LX + qw0 + lr) * HD
                                      + h * DA + ks * 32 + lg * 8];
        qfB[ks] = *(const short8*)&Qg[(size_t)(b * LX + qw1 + lr) * HD
                                      + h * DA + ks * 32 + lg * 8];
    }

    float mrunA = -1e30f, lrunA = 0.f, mrunB = -1e30f, lrunB = 0.f;
    f32x4 oA[4], oB[4];
    #pragma unroll
    for (int mj = 0; mj < 4; ++mj) { oA[mj] = 0.f; oB[mj] = 0.f; }

    // K staging via GL16: thread stages chunks t and t+256.
    const int zs0 = t >> 3, zs1 = 32 + (t >> 3);
    const int cs = t & 7;
    const int gc0 = (cs ^ (zs0 & 7)) << 3;          // zs0&7 == zs1&7
    ushort* kdst0 = &Ks[w * 512];
    ushort* kdst1 = &Ks[2048 + w * 512];
    const size_t kbase = (size_t)(b * LZ) * 1024 + h * DA;
    // V staging via GL16 from VT: chunk p -> m = p>>3, zc = (p&7) ^ f(m).
    const int vm0 = t >> 3, vm1 = 32 + (t >> 3);
    const int vq = t & 7;
    const int vf0 = (vm0 ^ (vm0 >> 3)) & 7;
    const int vf1 = (vm1 ^ (vm1 >> 3)) & 7;
    const int voff0 = ((vq ^ vf0) << 3);
    const int voff1 = ((vq ^ vf1) << 3);
    ushort* vdst0 = &Vt[w * 512];
    ushort* vdst1 = &Vt[2048 + w * 512];
    const size_t vtb0 = (size_t)(h * 64 + vm0) * 4096 + b * LZ;
    const size_t vtb1 = (size_t)(h * 64 + vm1) * 4096 + b * LZ;

    // one tile-compute phase for a strip (macro keeps static indexing)
#define STRIP_COMPUTE(QW, QF, MRUN, LRUN, OO, MIXBIT)                          \
    do {                                                                       \
        f32x4 s[4];                                                           \
        __builtin_amdgcn_s_setprio(1);                                        \
        _Pragma("unroll")                                                      \
        for (int nj = 0; nj < 4; ++nj) {                                      \
            const int row = nj * 16 + lr;                                     \
            const int sw = row & 7;                                           \
            const short8 kf0 = *(const short8*)&Ks[row * 64 + ((lg ^ sw) << 3)];\
            const short8 kf1 = *(const short8*)&Ks[row * 64 + (((4 + lg) ^ sw) << 3)];\
            f32x4 z4 = 0.f;                                                   \
            z4 = __builtin_amdgcn_mfma_f32_16x16x32_bf16(kf0, (QF)[0], z4, 0, 0, 0);\
            z4 = __builtin_amdgcn_mfma_f32_16x16x32_bf16(kf1, (QF)[1], z4, 0, 0, 0);\
            s[nj] = z4;                                                       \
        }                                                                      \
        __builtin_amdgcn_s_setprio(0);                                        \
        if (MIXBIT) {                                                          \
            const size_t arow = (size_t)(b * LX + (QW) + lr) * LZ + z0;       \
            _Pragma("unroll")                                                  \
            for (int nj = 0; nj < 4; ++nj)                                    \
                _Pragma("unroll")                                              \
                for (int r = 0; r < 4; ++r) {                                 \
                    const int z = nj * 16 + lg * 4 + r;                       \
                    const int ok = (amask[arow + z] != 0) & (pmask[b * LZ + z0 + z] != 0);\
                    if (!ok) s[nj][r] = MINF;                                 \
                }                                                              \
        }                                                                      \
        {                                                                      \
            float pm = s[0][0];                                               \
            _Pragma("unroll")                                                  \
            for (int nj = 0; nj < 4; ++nj)                                    \
                _Pragma("unroll")                                              \
                for (int r = 0; r < 4; ++r) pm = fmaxf(pm, s[nj][r]);         \
            pm = fmaxf(pm, __shfl_xor(pm, 16));                               \
            pm = fmaxf(pm, __shfl_xor(pm, 32));                               \
            if (__any(pm > (MRUN) + DTHR)) {                                  \
                const float mn = fmaxf((MRUN), pm);                           \
                const float al = exp2f((MRUN) - mn);                          \
                (MRUN) = mn;                                                  \
                (LRUN) *= al;                                                 \
                _Pragma("unroll")                                              \
                for (int r = 0; r < 4; ++r) {                                 \
                    const float alq = __shfl(al, (lg << 2) + r);              \
                    _Pragma("unroll")                                          \
                    for (int mj = 0; mj < 4; ++mj) (OO)[mj][r] *= alq;        \
                }                                                              \
            }                                                                  \
            _Pragma("unroll")                                                  \
            for (int nj = 0; nj < 4; ++nj)                                    \
                _Pragma("unroll")                                              \
                for (int r = 0; r < 4; ++r) {                                 \
                    const float p = exp2f(s[nj][r] - (MRUN));                 \
                    s[nj][r] = p;                                             \
                    (LRUN) += p;                                              \
                }                                                              \
        }                                                                      \
        short8 pa[2];                                                         \
        {                                                                      \
            uint32_t pk01[4], pk23[4];                                        \
            _Pragma("unroll")                                                  \
            for (int nj = 0; nj < 4; ++nj) {                                  \
                pk01[nj] = cvtpk(s[nj][0], s[nj][1]);                         \
                pk23[nj] = cvtpk(s[nj][2], s[nj][3]);                         \
            }                                                                  \
            _Pragma("unroll")                                                  \
            for (int ks = 0; ks < 2; ++ks) {                                  \
                union { uint32_t d[4]; short8 v; } u;                         \
                u.d[0] = pk01[2 * ks];                                        \
                u.d[1] = pk23[2 * ks];                                        \
                u.d[2] = pk01[2 * ks + 1];                                    \
                u.d[3] = pk23[2 * ks + 1];                                    \
                pa[ks] = u.v;                                                 \
            }                                                                  \
        }                                                                      \
        __builtin_amdgcn_s_setprio(1);                                        \
        _Pragma("unroll")                                                      \
        for (int mj = 0; mj < 4; ++mj) {                                      \
            const int m_ = mj * 16 + lr;                                      \
            const int xr = (m_ ^ (m_ >> 3)) & 7;                              \
            const int czb = lg >> 1;                                          \
            const int zo = (lg & 1) * 4;                                      \
            _Pragma("unroll")                                                  \
            for (int ks = 0; ks < 2; ++ks) {                                  \
                const int clo = (ks * 4 + czb) ^ xr;                          \
                const int chi = (ks * 4 + 2 + czb) ^ xr;                      \
                const uint2 lo = *(const uint2*)&Vt[m_ * 64 + ((clo & 7) << 3) + zo];\
                const uint2 hi = *(const uint2*)&Vt[m_ * 64 + ((chi & 7) << 3) + zo];\
                union { uint32_t d[4]; short8 v; } u;                         \
                u.d[0] = lo.x; u.d[1] = lo.y; u.d[2] = hi.x; u.d[3] = hi.y;   \
                (OO)[mj] = __builtin_amdgcn_mfma_f32_16x16x32_bf16(pa[ks], u.v, (OO)[mj], 0, 0, 0);\
            }                                                                  \
        }                                                                      \
        __builtin_amdgcn_s_setprio(0);                                        \
    } while (0)

    uint32_t remU = act0 | act1;
    while (remU) {
        const int zb = __builtin_ctz(remU);
        remU &= remU - 1;
        const int z0 = zb * 64;

        __syncthreads();                // prior tile's LDS reads done
        GL16(&Kb[kbase + (size_t)(z0 + zs0) * 1024 + gc0], kdst0);
        GL16(&Kb[kbase + (size_t)(z0 + zs1) * 1024 + gc0], kdst1);
        GL16(&VTg[vtb0 + z0 + voff0], vdst0);
        GL16(&VTg[vtb1 + z0 + voff1], vdst1);
        __syncthreads();                // drains vmcnt: K + V visible

        if ((act0 >> zb) & 1)
            STRIP_COMPUTE(qw0, qfA, mrunA, lrunA, (&oA[0] - 0), ((mix0 >> zb) & 1));
        if ((act1 >> zb) & 1)
            STRIP_COMPUTE(qw1, qfB, mrunB, lrunB, (&oB[0] - 0), ((mix1 >> zb) & 1));
    }
#undef STRIP_COMPUTE

    // ---- epilogue: finish l reductions, store both strips' partials ----
    lrunA += __shfl_xor(lrunA, 16);
    lrunA += __shfl_xor(lrunA, 32);
    lrunB += __shfl_xor(lrunB, 16);
    lrunB += __shfl_xor(lrunB, 32);
    if (l < 16) {
        ml[(size_t)((sKV * NB + b) * HH + h) * LX + qw0 + l] = make_float2(mrunA, lrunA);
        ml[(size_t)((sKV * NB + b) * HH + h) * LX + qw1 + l] = make_float2(mrunB, lrunB);
    }
    const size_t ob0 = (size_t)((sKV * NB + b) * LX + qw0) * HD + h * DM;
    const size_t ob1 = (size_t)((sKV * NB + b) * LX + qw1) * HD + h * DM;
    #pragma unroll
    for (int r = 0; r < 4; ++r)
        #pragma unroll
        for (int mj = 0; mj < 4; ++mj) {
            Op[ob0 + (size_t)((lg << 2) + r) * HD + mj * 16 + lr] = f2bf(oA[mj][r]);
            Op[ob1 + (size_t)((lg << 2) + r) * HD + mj * 16 + lr] = f2bf(oB[mj][r]);
        }
}

// ---------------------------------------------------------------------------
// Output GEMM with fused split-KV combine AND in-kernel combine weights.
// Tile 64x128, BK=32, 4 waves; fp32 out + bias.
// ---------------------------------------------------------------------------
__global__ __launch_bounds__(256) void gemm_out_fused(
    const ushort* __restrict__ Op, const float2* __restrict__ ml,
    const ushort* __restrict__ Bt, const float* __restrict__ bias,
    float* __restrict__ Cout)
{
    __shared__ ushort As[64 * 32];
    __shared__ ushort Bs[128 * 32];
    __shared__ float2 Wl[64][17];
    const int t = threadIdx.x;
    const int w = t >> 6, l = t & 63, lr = l & 15, lg = l >> 4;
    const int wr = w >> 1, wc = w & 1;
    const int n0 = blockIdx.x * 128, m0 = blockIdx.y * 64;

    {
        const int e = t * 4;
        #pragma unroll
        for (int j = 0; j < 4; ++j) {
            const int rl = (e + j) >> 4, hh = (e + j) & 15;
            const int ra = m0 + rl;
            const int bb = ra >> 11, xx = ra & 2047;
            const float2 a0 = ml[(size_t)(bb * HH + hh) * LX + xx];
            const float2 a1 = ml[(size_t)((NB + bb) * HH + hh) * LX + xx];
            const float M = fmaxf(a0.x, a1.x);
            const float w0 = exp2f(a0.x - M), w1 = exp2f(a1.x - M);
            const float inv = 1.f / fmaxf(a0.y * w0 + a1.y * w1, 1e-37f);
            Wl[rl][hh] = make_float2(w0 * inv, w1 * inv);
        }
    }
    __syncthreads();

    const int ra = m0 + (t >> 2), ka = (t & 3) * 8;
    const ushort* p0 = &Op[(size_t)ra * HD + ka];
    const ushort* p1 = p0 + (size_t)NB * LX * HD;
    const ushort* b0 = &Bt[(size_t)(n0 + (t >> 2)) * 1024 + ka];
    const ushort* b1 = &Bt[(size_t)(n0 + 64 + (t >> 2)) * 1024 + ka];
    ushort* lB0 = &Bs[w * 512];
    ushort* lB1 = &Bs[(4 + w) * 512];

    f32x4 acc[2][4];
    #pragma unroll
    for (int i = 0; i < 2; ++i)
        #pragma unroll
        for (int j = 0; j < 4; ++j) acc[i][j] = 0.f;

    for (int k0 = 0; k0 < 1024; k0 += 32) {
        const short8 q0 = *(const short8*)(p0 + k0);
        const short8 q1 = *(const short8*)(p1 + k0);
        const float2 wv = Wl[t >> 2][(k0 + ka) >> 6];
        union { ushort d[8]; short8 v; } av;
        #pragma unroll
        for (int j = 0; j < 8; ++j)
            av.d[j] = f2bf(bf2f((ushort)q0[j]) * wv.x + bf2f((ushort)q1[j]) * wv.y);
        __syncthreads();
        *(short8*)&As[t * 8] = av.v;
        GL16(b0 + k0, lB0);
        GL16(b1 + k0, lB1);
        __syncthreads();
        short8 af[2], bf[4];
        #pragma unroll
        for (int mi = 0; mi < 2; ++mi)
            af[mi] = *(const short8*)&As[(wr * 32 + mi * 16 + lr) * 32 + lg * 8];
        #pragma unroll
        for (int nj = 0; nj < 4; ++nj)
            bf[nj] = *(const short8*)&Bs[(wc * 64 + nj * 16 + lr) * 32 + lg * 8];
        #pragma unroll
        for (int mi = 0; mi < 2; ++mi)
            #pragma unroll
            for (int nj = 0; nj < 4; ++nj)
                acc[mi][nj] = __builtin_amdgcn_mfma_f32_16x16x32_bf16(
                    af[mi], bf[nj], acc[mi][nj], 0, 0, 0);
    }

    const int row0 = m0 + wr * 32, col0 = n0 + wc * 64;
    #pragma unroll
    for (int mi = 0; mi < 2; ++mi)
        #pragma unroll
        for (int nj = 0; nj < 4; ++nj) {
            const int col = col0 + nj * 16 + lr;
            #pragma unroll
            for (int r = 0; r < 4; ++r) {
                const int row = row0 + mi * 16 + lg * 4 + r;
                Cout[(size_t)row * 1024 + col] = acc[mi][nj][r] + bias[col];
            }
        }
}

// ---------------------------------------------------------------------------
extern "C" void kernel_launch(void* const* d_in, const int* in_sizes, int n_in,
                              void* d_out, int out_size, void* d_ws, size_t ws_size,
                              hipStream_t stream)
{
    const float* primary = (const float*)d_in[0];
    const float* context = (const float*)d_in[1];
    const int*   pmask   = (const int*)d_in[2];
    const int*   amask   = (const int*)d_in[3];
    const float* Wq      = (const float*)d_in[4];
    const float* Wk      = (const float*)d_in[5];
    const float* Wv      = (const float*)d_in[6];
    const float* Wo      = (const float*)d_in[7];
    const float* bo      = (const float*)d_in[8];
    float* out = (float*)d_out;

    char* w8 = (char*)d_ws;
    ushort* Pb  = (ushort*)(w8 + 0);          // dead after gemm_qkv -> Op alias
    ushort* Cb  = (ushort*)(w8 + 8388608);
    ushort* Qb  = (ushort*)(w8 + 16777216);
    ushort* Kb  = (ushort*)(w8 + 25165824);   // [4096][1024] bf16 = 8 MB
    ushort* VT  = (ushort*)(w8 + 33554432);   // [1024][4096] bf16 = 8 MB
    ushort* Wqt = (ushort*)(w8 + 50331648);   // dead after gemm_qkv -> ml alias
    ushort* Wkt = (ushort*)(w8 + 52428800);   // [WkT;WvT] fused 2048x1024
    ushort* Wvt = (ushort*)(w8 + 54525952);
    ushort* Wot = (ushort*)(w8 + 56623104);
    int*    clsp = (int*)(w8 + 58720256);
    ushort* Op   = Pb;                        // 2 x 8.4 MB partials (Pb+Cb)
    float2* mlp  = (float2*)Wqt;              // 1 MB

    prep<<<11264, 256, 0, stream>>>(primary, context, Pb, Cb,
                                    Wq, Wk, Wv, Wo, Wqt, Wkt, Wvt, Wot,
                                    amask, pmask, clsp);
    gemm_qkv<<<dim3(24, 32), 256, 0, stream>>>(Pb, Cb, Wqt, Wkt, Qb, Kb, VT);
    attn_mfma<<<dim3(16, 16, 4), 256, 0, stream>>>(Qb, Kb, VT, amask, pmask, clsp, Op, mlp);
    gemm_out_fused<<<dim3(8, 64), 256, 0, stream>>>(Op, mlp, Wot, bo, out);
}

// Round 21
// 131.515 us; speedup vs baseline: 1.1022x; 1.1022x over previous
//
#include <hip/hip_runtime.h>

#define NB 2
#define LX 2048
#define LZ 2048
#define HH 16
#define DA 64
#define DM 64
#define HD 1024
#define KVS 2048              // fused K|V buffer row stride
#define MINF  -1000000.0f
#define QSC   0.1803368801f   // 0.125 * log2(e): softmax done in base-2 domain
#define DTHR  8.0f            // defer-max threshold (base-2): P <= 2^8

typedef __attribute__((ext_vector_type(8))) short short8;
typedef __attribute__((ext_vector_type(4))) float f32x4;

static __device__ __forceinline__ ushort f2bf(float f) {
    union { float f; uint32_t u; } c; c.f = f;
    return (ushort)((c.u + 0x7FFFu + ((c.u >> 16) & 1u)) >> 16);
}

static __device__ __forceinline__ float bf2f(ushort u) {
    union { uint32_t u; float f; } c; c.u = (uint32_t)u << 16;
    return c.f;
}

static __device__ __forceinline__ uint32_t cvtpk(float lo, float hi) {
    uint32_t r;
    asm("v_cvt_pk_bf16_f32 %0, %1, %2" : "=v"(r) : "v"(lo), "v"(hi));
    return r;
}

#define GL16(g, l) __builtin_amdgcn_global_load_lds( \
    (const __attribute__((address_space(1))) void*)(g), \
    (__attribute__((address_space(3))) void*)(l), 16, 0, 0)

// ---------------------------------------------------------------------------
// Fused preprocessing, one launch (11264 blocks):
//   [0,8192)      fp32->bf16 of both activations
//   [8192,9216)   4 weight transposes (f32 [K][N] -> bf16 [N][K])
//   [9216,11264)  mask tile classification (0 all-masked / 1 all-pass / 2 mix)
// ---------------------------------------------------------------------------
__global__ __launch_bounds__(256) void prep(
    const float* __restrict__ pA, const float* __restrict__ pB,
    ushort* __restrict__ oA, ushort* __restrict__ oB,
    const float* __restrict__ W0, const float* __restrict__ W1,
    const float* __restrict__ W2, const float* __restrict__ W3,
    ushort* __restrict__ T0, ushort* __restrict__ T1,
    ushort* __restrict__ T2, ushort* __restrict__ T3,
    const int* __restrict__ amask, const int* __restrict__ pmask,
    int* __restrict__ cls)
{
    const int fid = blockIdx.x;
    const int t = threadIdx.x;
    if (fid < 8192) {
        const int i = fid * 256 + t;
        const float* in = (i < 1048576) ? pA : pB;
        ushort* out = (i < 1048576) ? oA : oB;
        const int j = i & 1048575;
        float4 v = ((const float4*)in)[j];
        ushort4 o;
        o.x = f2bf(v.x); o.y = f2bf(v.y); o.z = f2bf(v.z); o.w = f2bf(v.w);
        ((ushort4*)out)[j] = o;
    } else if (fid < 9216) {
        __shared__ ushort Ls[64][72];
        const int id2 = fid - 8192;                 // 0..1023
        const int zz = id2 >> 8, rem = id2 & 255;
        const float* W = (zz == 0) ? W0 : (zz == 1) ? W1 : (zz == 2) ? W2 : W3;
        ushort* Wt = (zz == 0) ? T0 : (zz == 1) ? T1 : (zz == 2) ? T2 : T3;
        const int n0 = (rem & 15) * 64, k0 = (rem >> 4) * 64;
        const int rr = t >> 4, c4 = (t & 15) * 4;
        #pragma unroll
        for (int i = 0; i < 4; ++i) {
            const int r = rr + i * 16;
            float4 v = *(const float4*)&W[(size_t)(k0 + r) * 1024 + n0 + c4];
            Ls[c4 + 0][r] = f2bf(v.x);
            Ls[c4 + 1][r] = f2bf(v.y);
            Ls[c4 + 2][r] = f2bf(v.z);
            Ls[c4 + 3][r] = f2bf(v.w);
        }
        __syncthreads();
        const int n = t >> 2, kc = (t & 3) * 16;
        *(short8*)&Wt[(size_t)(n0 + n) * 1024 + k0 + kc]     = *(const short8*)&Ls[n][kc];
        *(short8*)&Wt[(size_t)(n0 + n) * 1024 + k0 + kc + 8] = *(const short8*)&Ls[n][kc + 8];
    } else {
        const int bid = fid - 9216;                 // 0..2047
        const int b = bid >> 10, xb = (bid >> 5) & 31, zb = bid & 31;
        int andv = 1, orv = 0;
        #pragma unroll
        for (int i = 0; i < 16; ++i) {
            const int e = t + i * 256;
            const int r = e >> 6, z = e & 63;
            const int m = amask[((size_t)b * LX + xb * 64 + r) * LZ + zb * 64 + z];
            const int p = pmask[(size_t)b * LZ + zb * 64 + z];
            const int v = (m != 0) & (p != 0);
            andv &= v; orv |= v;
        }
        __shared__ int sa[256];
        __shared__ int so[256];
        sa[t] = andv; so[t] = orv;
        __syncthreads();
        for (int s = 128; s > 0; s >>= 1) {
            if (t < s) { sa[t] &= sa[t + s]; so[t] |= so[t + s]; }
            __syncthreads();
        }
        if (t == 0) cls[bid] = so[0] ? (sa[0] ? 1 : 2) : 0;
    }
}

// ---------------------------------------------------------------------------
// Fused Q + KV projection GEMM (m97 structure, 128x128 tile, BK=32).
// bx<8: Q = primary @ WqT (x QSC), out stride 1024.
// bx>=8: [K|V] = context @ [WkT;WvT] (2048 cols), out stride 2048.
// ---------------------------------------------------------------------------
__global__ __launch_bounds__(256) void gemm_qkv(
    const ushort* __restrict__ Pb, const ushort* __restrict__ Cb,
    const ushort* __restrict__ Wqt, const ushort* __restrict__ Wkvt,
    ushort* __restrict__ Qb, ushort* __restrict__ KV)
{
    const int bx = blockIdx.x;
    const bool isQ = bx < 8;
    const ushort* A  = isQ ? Pb : Cb;
    const ushort* Bt = isQ ? Wqt : Wkvt;
    ushort* Cout = isQ ? Qb : KV;
    const int n0 = (isQ ? bx : bx - 8) * 128;
    const int ostr = isQ ? 1024 : KVS;
    const float osc = isQ ? QSC : 1.0f;

    __shared__ ushort As[128 * 32];
    __shared__ ushort Bs[128 * 32];
    const int t = threadIdx.x;
    const int w = t >> 6, l = t & 63, lr = l & 15, lg = l >> 4;
    const int wr = w >> 1, wc = w & 1;
    const int m0 = blockIdx.y * 128;

    const int c0 = t, c1 = t + 256;
    const ushort* a0 = &A[(size_t)(m0 + (c0 >> 2)) * 1024 + (c0 & 3) * 8];
    const ushort* a1 = &A[(size_t)(m0 + (c1 >> 2)) * 1024 + (c1 & 3) * 8];
    const ushort* b0 = &Bt[(size_t)(n0 + (c0 >> 2)) * 1024 + (c0 & 3) * 8];
    const ushort* b1 = &Bt[(size_t)(n0 + (c1 >> 2)) * 1024 + (c1 & 3) * 8];
    ushort* lA0 = &As[w * 512];
    ushort* lA1 = &As[(4 + w) * 512];
    ushort* lB0 = &Bs[w * 512];
    ushort* lB1 = &Bs[(4 + w) * 512];

    f32x4 acc[4][4];
    #pragma unroll
    for (int i = 0; i < 4; ++i)
        #pragma unroll
        for (int j = 0; j < 4; ++j) acc[i][j] = 0.f;

    for (int k0 = 0; k0 < 1024; k0 += 32) {
        __syncthreads();
        GL16(a0 + k0, lA0);
        GL16(a1 + k0, lA1);
        GL16(b0 + k0, lB0);
        GL16(b1 + k0, lB1);
        __syncthreads();
        short8 af[4], bf[4];
        #pragma unroll
        for (int mi = 0; mi < 4; ++mi)
            af[mi] = *(const short8*)&As[(wr * 64 + mi * 16 + lr) * 32 + lg * 8];
        #pragma unroll
        for (int nj = 0; nj < 4; ++nj)
            bf[nj] = *(const short8*)&Bs[(wc * 64 + nj * 16 + lr) * 32 + lg * 8];
        #pragma unroll
        for (int mi = 0; mi < 4; ++mi)
            #pragma unroll
            for (int nj = 0; nj < 4; ++nj)
                acc[mi][nj] = __builtin_amdgcn_mfma_f32_16x16x32_bf16(
                    af[mi], bf[nj], acc[mi][nj], 0, 0, 0);
    }

    const int row0 = m0 + wr * 64, col0 = n0 + wc * 64;
    #pragma unroll
    for (int mi = 0; mi < 4; ++mi)
        #pragma unroll
        for (int nj = 0; nj < 4; ++nj) {
            const int col = col0 + nj * 16 + lr;
            #pragma unroll
            for (int r = 0; r < 4; ++r) {
                const int row = row0 + mi * 16 + lg * 4 + r;
                Cout[(size_t)row * ostr + col] = f2bf(acc[mi][nj][r] * osc);
            }
        }
}

// ---------------------------------------------------------------------------
// MFMA flash attention, qb-paired + STAGE-ONCE-COMPUTE-TWICE: single outer
// zb walk over the union of both strips' active tiles; each staged K/V tile
// feeds both strips (qb=p and qb=31-p) back-to-back. Stagings per block drop
// 33 -> ~16.5 (halved V-pack VALU, halved barriers, halved K/V L2 traffic);
// compute phases densify. Per-strip state (qf/o/m/l) statically unrolled.
// Split-KV x2 (1024 uniform blocks, 4/CU), balanced XCD clustering; K via
// GL16 w/ pre-XOR'd global source (0 conflicts); V reg-staged chunk-XOR LDS;
// swapped QK^T; zero-shuffle PV (sigma z-order); defer-max; deferred
// l-reduction; setprio(1) on MFMA. Writes PARTIAL O (bf16) + (m,l) f32.
// ---------------------------------------------------------------------------
__global__ __launch_bounds__(256, 4) void attn_mfma(
    const ushort* __restrict__ Qg, const ushort* __restrict__ KVg,
    const int* __restrict__ amask, const int* __restrict__ pmask,
    const int* __restrict__ cls, ushort* __restrict__ Op,
    float2* __restrict__ ml)
{
    __shared__ ushort Ks[64 * 64];   // [z][d-chunk swizzled], linear for GL16
    __shared__ ushort Vt[64 * 64];   // [m][z], chunk-XOR swizzled

    const int t = threadIdx.x, w = t >> 6, l = t & 63, lr = l & 15, lg = l >> 4;
    // balanced XCD clustering over 1024 blocks: XCD x gets groups {x,x+8,..}
    const int flat = blockIdx.x + 16 * (blockIdx.y + 16 * blockIdx.z); // 0..1023
    const int xcd = flat & 7, ii = flat >> 3;       // ii 0..127
    const int g = xcd + 8 * (ii >> 4);              // 0..63 (h,bs) group
    const int pp = ii & 15;                         // pair index 0..15
    const int h = g & 15, bs = g >> 4;              // bs 0..3
    const int b = bs & 1, sKV = bs >> 1;
    const uint32_t halfm = sKV ? 0xAAAAAAAAu : 0x55555555u;

    // per-strip setup (statically indexed throughout)
    const int qb0 = pp, qb1 = 31 - pp;
    const int qw0 = qb0 * 64 + w * 16, qw1 = qb1 * 64 + w * 16;
    const int cv0 = cls[b * 1024 + qb0 * 32 + (l & 31)];
    const int cv1 = cls[b * 1024 + qb1 * 32 + (l & 31)];
    const uint32_t act0 = (uint32_t)__ballot(cv0 != 0) & halfm;
    const uint32_t mix0 = (uint32_t)__ballot(cv0 == 2) & halfm;
    const uint32_t act1 = (uint32_t)__ballot(cv1 != 0) & halfm;
    const uint32_t mix1 = (uint32_t)__ballot(cv1 == 2) & halfm;

    // Q B-frags per strip: lane holds Q[q = lr][d = ks*32 + lg*8 .. +8]
    short8 qfA[2], qfB[2];
    #pragma unroll
    for (int ks = 0; ks < 2; ++ks) {
        qfA[ks] = *(const short8*)&Qg[(size_t)(b * LX + qw0 + lr) * HD
                                      + h * DA + ks * 32 + lg * 8];
        qfB[ks] = *(const short8*)&Qg[(size_t)(b * LX + qw1 + lr) * HD
                                      + h * DA + ks * 32 + lg * 8];
    }

    float mrunA = -1e30f, lrunA = 0.f, mrunB = -1e30f, lrunB = 0.f;
    f32x4 oA[4], oB[4];
    #pragma unroll
    for (int mj = 0; mj < 4; ++mj) { oA[mj] = 0.f; oB[mj] = 0.f; }

    // K staging via GL16: thread stages chunks t and t+256.
    const int zs0 = t >> 3, zs1 = 32 + (t >> 3);
    const int cs = t & 7;
    const int gc0 = (cs ^ (zs0 & 7)) << 3;          // zs0&7 == zs1&7
    ushort* kdst0 = &Ks[w * 512];
    ushort* kdst1 = &Ks[2048 + w * 512];
    const size_t kbase = (size_t)(b * LZ) * KVS + h * DA;
    const int vz = (t >> 3) * 2, vc = (t & 7) * 8; // V staging (2 rows x 8 cols)

    // one tile-compute phase for a strip (macro to keep static indexing)
#define STRIP_COMPUTE(QW, QF, MRUN, LRUN, OO, MIXBIT)                          \
    do {                                                                       \
        f32x4 s[4];                                                           \
        __builtin_amdgcn_s_setprio(1);                                        \
        _Pragma("unroll")                                                      \
        for (int nj = 0; nj < 4; ++nj) {                                      \
            const int row = nj * 16 + lr;                                     \
            const int sw = row & 7;                                           \
            const short8 kf0 = *(const short8*)&Ks[row * 64 + ((lg ^ sw) << 3)];\
            const short8 kf1 = *(const short8*)&Ks[row * 64 + (((4 + lg) ^ sw) << 3)];\
            f32x4 z4 = 0.f;                                                   \
            z4 = __builtin_amdgcn_mfma_f32_16x16x32_bf16(kf0, (QF)[0], z4, 0, 0, 0);\
            z4 = __builtin_amdgcn_mfma_f32_16x16x32_bf16(kf1, (QF)[1], z4, 0, 0, 0);\
            s[nj] = z4;                                                       \
        }                                                                      \
        __builtin_amdgcn_s_setprio(0);                                        \
        if (MIXBIT) {                                                          \
            const size_t arow = (size_t)(b * LX + (QW) + lr) * LZ + z0;       \
            _Pragma("unroll")                                                  \
            for (int nj = 0; nj < 4; ++nj)                                    \
                _Pragma("unroll")                                              \
                for (int r = 0; r < 4; ++r) {                                 \
                    const int z = nj * 16 + lg * 4 + r;                       \
                    const int ok = (amask[arow + z] != 0) & (pmask[b * LZ + z0 + z] != 0);\
                    if (!ok) s[nj][r] = MINF;                                 \
                }                                                              \
        }                                                                      \
        {                                                                      \
            float pm = s[0][0];                                               \
            _Pragma("unroll")                                                  \
            for (int nj = 0; nj < 4; ++nj)                                    \
                _Pragma("unroll")                                              \
                for (int r = 0; r < 4; ++r) pm = fmaxf(pm, s[nj][r]);         \
            pm = fmaxf(pm, __shfl_xor(pm, 16));                               \
            pm = fmaxf(pm, __shfl_xor(pm, 32));                               \
            if (__any(pm > (MRUN) + DTHR)) {                                  \
                const float mn = fmaxf((MRUN), pm);                           \
                const float al = exp2f((MRUN) - mn);                          \
                (MRUN) = mn;                                                  \
                (LRUN) *= al;                                                 \
                _Pragma("unroll")                                              \
                for (int r = 0; r < 4; ++r) {                                 \
                    const float alq = __shfl(al, (lg << 2) + r);              \
                    _Pragma("unroll")                                          \
                    for (int mj = 0; mj < 4; ++mj) (OO)[mj][r] *= alq;        \
                }                                                              \
            }                                                                  \
            _Pragma("unroll")                                                  \
            for (int nj = 0; nj < 4; ++nj)                                    \
                _Pragma("unroll")                                              \
                for (int r = 0; r < 4; ++r) {                                 \
                    const float p = exp2f(s[nj][r] - (MRUN));                 \
                    s[nj][r] = p;                                             \
                    (LRUN) += p;                                              \
                }                                                              \
        }                                                                      \
        short8 pa[2];                                                         \
        {                                                                      \
            uint32_t pk01[4], pk23[4];                                        \
            _Pragma("unroll")                                                  \
            for (int nj = 0; nj < 4; ++nj) {                                  \
                pk01[nj] = cvtpk(s[nj][0], s[nj][1]);                         \
                pk23[nj] = cvtpk(s[nj][2], s[nj][3]);                         \
            }                                                                  \
            _Pragma("unroll")                                                  \
            for (int ks = 0; ks < 2; ++ks) {                                  \
                union { uint32_t d[4]; short8 v; } u;                         \
                u.d[0] = pk01[2 * ks];                                        \
                u.d[1] = pk23[2 * ks];                                        \
                u.d[2] = pk01[2 * ks + 1];                                    \
                u.d[3] = pk23[2 * ks + 1];                                    \
                pa[ks] = u.v;                                                 \
            }                                                                  \
        }                                                                      \
        __builtin_amdgcn_s_setprio(1);                                        \
        _Pragma("unroll")                                                      \
        for (int mj = 0; mj < 4; ++mj) {                                      \
            const int m_ = mj * 16 + lr;                                      \
            const int xr = (m_ ^ (m_ >> 3)) & 7;                              \
            const int czb = lg >> 1;                                          \
            const int zo = (lg & 1) * 4;                                      \
            _Pragma("unroll")                                                  \
            for (int ks = 0; ks < 2; ++ks) {                                  \
                const int clo = (ks * 4 + czb) ^ xr;                          \
                const int chi = (ks * 4 + 2 + czb) ^ xr;                      \
                const uint2 lo = *(const uint2*)&Vt[m_ * 64 + ((clo & 7) << 3) + zo];\
                const uint2 hi = *(const uint2*)&Vt[m_ * 64 + ((chi & 7) << 3) + zo];\
                union { uint32_t d[4]; short8 v; } u;                         \
                u.d[0] = lo.x; u.d[1] = lo.y; u.d[2] = hi.x; u.d[3] = hi.y;   \
                (OO)[mj] = __builtin_amdgcn_mfma_f32_16x16x32_bf16(pa[ks], u.v, (OO)[mj], 0, 0, 0);\
            }                                                                  \
        }                                                                      \
        __builtin_amdgcn_s_setprio(0);                                        \
    } while (0)

    uint32_t remU = act0 | act1;
    while (remU) {
        const int zb = __builtin_ctz(remU);
        remU &= remU - 1;
        const int z0 = zb * 64;

        __syncthreads();                // prior tile's LDS reads done
        GL16(&KVg[kbase + (size_t)(z0 + zs0) * KVS + gc0], kdst0);
        GL16(&KVg[kbase + (size_t)(z0 + zs1) * KVS + gc0], kdst1);
        {
            const ushort* vp = &KVg[(size_t)(b * LZ + z0 + vz) * KVS + 1024 + h * DM + vc];
            short8 v0 = *(const short8*)vp;
            short8 v1 = *(const short8*)(vp + KVS);
            const int zc = vz >> 3, zo = vz & 7;
            #pragma unroll
            for (int j = 0; j < 8; ++j) {
                const int m = vc + j;
                const int idx = m * 64 + (((zc ^ m ^ (m >> 3)) & 7) << 3) + zo;
                *(uint32_t*)&Vt[idx] =
                    (uint32_t)(ushort)v0[j] | ((uint32_t)(ushort)v1[j] << 16);
            }
        }
        __syncthreads();                // drains vmcnt: K + V visible

        if ((act0 >> zb) & 1)
            STRIP_COMPUTE(qw0, qfA, mrunA, lrunA, (&oA[0] - 0), ((mix0 >> zb) & 1));
        if ((act1 >> zb) & 1)
            STRIP_COMPUTE(qw1, qfB, mrunB, lrunB, (&oB[0] - 0), ((mix1 >> zb) & 1));
    }
#undef STRIP_COMPUTE

    // ---- epilogue: finish l reductions, store both strips' partials ----
    lrunA += __shfl_xor(lrunA, 16);
    lrunA += __shfl_xor(lrunA, 32);
    lrunB += __shfl_xor(lrunB, 16);
    lrunB += __shfl_xor(lrunB, 32);
    if (l < 16) {
        ml[(size_t)((sKV * NB + b) * HH + h) * LX + qw0 + l] = make_float2(mrunA, lrunA);
        ml[(size_t)((sKV * NB + b) * HH + h) * LX + qw1 + l] = make_float2(mrunB, lrunB);
    }
    const size_t ob0 = (size_t)((sKV * NB + b) * LX + qw0) * HD + h * DM;
    const size_t ob1 = (size_t)((sKV * NB + b) * LX + qw1) * HD + h * DM;
    #pragma unroll
    for (int r = 0; r < 4; ++r)
        #pragma unroll
        for (int mj = 0; mj < 4; ++mj) {
            Op[ob0 + (size_t)((lg << 2) + r) * HD + mj * 16 + lr] = f2bf(oA[mj][r]);
            Op[ob1 + (size_t)((lg << 2) + r) * HD + mj * 16 + lr] = f2bf(oB[mj][r]);
        }
}

// ---------------------------------------------------------------------------
// Output GEMM with fused split-KV combine AND in-kernel combine weights.
// Tile 64x128, BK=32, 4 waves; fp32 out + bias.
// ---------------------------------------------------------------------------
__global__ __launch_bounds__(256) void gemm_out_fused(
    const ushort* __restrict__ Op, const float2* __restrict__ ml,
    const ushort* __restrict__ Bt, const float* __restrict__ bias,
    float* __restrict__ Cout)
{
    __shared__ ushort As[64 * 32];
    __shared__ ushort Bs[128 * 32];
    __shared__ float2 Wl[64][17];
    const int t = threadIdx.x;
    const int w = t >> 6, l = t & 63, lr = l & 15, lg = l >> 4;
    const int wr = w >> 1, wc = w & 1;
    const int n0 = blockIdx.x * 128, m0 = blockIdx.y * 64;

    {
        const int e = t * 4;
        #pragma unroll
        for (int j = 0; j < 4; ++j) {
            const int rl = (e + j) >> 4, hh = (e + j) & 15;
            const int ra = m0 + rl;
            const int bb = ra >> 11, xx = ra & 2047;
            const float2 a0 = ml[(size_t)(bb * HH + hh) * LX + xx];
            const float2 a1 = ml[(size_t)((NB + bb) * HH + hh) * LX + xx];
            const float M = fmaxf(a0.x, a1.x);
            const float w0 = exp2f(a0.x - M), w1 = exp2f(a1.x - M);
            const float inv = 1.f / fmaxf(a0.y * w0 + a1.y * w1, 1e-37f);
            Wl[rl][hh] = make_float2(w0 * inv, w1 * inv);
        }
    }
    __syncthreads();

    const int ra = m0 + (t >> 2), ka = (t & 3) * 8;
    const ushort* p0 = &Op[(size_t)ra * HD + ka];
    const ushort* p1 = p0 + (size_t)NB * LX * HD;
    const ushort* b0 = &Bt[(size_t)(n0 + (t >> 2)) * 1024 + ka];
    const ushort* b1 = &Bt[(size_t)(n0 + 64 + (t >> 2)) * 1024 + ka];
    ushort* lB0 = &Bs[w * 512];
    ushort* lB1 = &Bs[(4 + w) * 512];

    f32x4 acc[2][4];
    #pragma unroll
    for (int i = 0; i < 2; ++i)
        #pragma unroll
        for (int j = 0; j < 4; ++j) acc[i][j] = 0.f;

    for (int k0 = 0; k0 < 1024; k0 += 32) {
        const short8 q0 = *(const short8*)(p0 + k0);
        const short8 q1 = *(const short8*)(p1 + k0);
        const float2 wv = Wl[t >> 2][(k0 + ka) >> 6];
        union { ushort d[8]; short8 v; } av;
        #pragma unroll
        for (int j = 0; j < 8; ++j)
            av.d[j] = f2bf(bf2f((ushort)q0[j]) * wv.x + bf2f((ushort)q1[j]) * wv.y);
        __syncthreads();
        *(short8*)&As[t * 8] = av.v;
        GL16(b0 + k0, lB0);
        GL16(b1 + k0, lB1);
        __syncthreads();
        short8 af[2], bf[4];
        #pragma unroll
        for (int mi = 0; mi < 2; ++mi)
            af[mi] = *(const short8*)&As[(wr * 32 + mi * 16 + lr) * 32 + lg * 8];
        #pragma unroll
        for (int nj = 0; nj < 4; ++nj)
            bf[nj] = *(const short8*)&Bs[(wc * 64 + nj * 16 + lr) * 32 + lg * 8];
        #pragma unroll
        for (int mi = 0; mi < 2; ++mi)
            #pragma unroll
            for (int nj = 0; nj < 4; ++nj)
                acc[mi][nj] = __builtin_amdgcn_mfma_f32_16x16x32_bf16(
                    af[mi], bf[nj], acc[mi][nj], 0, 0, 0);
    }

    const int row0 = m0 + wr * 32, col0 = n0 + wc * 64;
    #pragma unroll
    for (int mi = 0; mi < 2; ++mi)
        #pragma unroll
        for (int nj = 0; nj < 4; ++nj) {
            const int col = col0 + nj * 16 + lr;
            #pragma unroll
            for (int r = 0; r < 4; ++r) {
                const int row = row0 + mi * 16 + lg * 4 + r;
                Cout[(size_t)row * 1024 + col] = acc[mi][nj][r] + bias[col];
            }
        }
}

// ---------------------------------------------------------------------------
extern "C" void kernel_launch(void* const* d_in, const int* in_sizes, int n_in,
                              void* d_out, int out_size, void* d_ws, size_t ws_size,
                              hipStream_t stream)
{
    const float* primary = (const float*)d_in[0];
    const float* context = (const float*)d_in[1];
    const int*   pmask   = (const int*)d_in[2];
    const int*   amask   = (const int*)d_in[3];
    const float* Wq      = (const float*)d_in[4];
    const float* Wk      = (const float*)d_in[5];
    const float* Wv      = (const float*)d_in[6];
    const float* Wo      = (const float*)d_in[7];
    const float* bo      = (const float*)d_in[8];
    float* out = (float*)d_out;

    char* w8 = (char*)d_ws;
    ushort* Pb  = (ushort*)(w8 + 0);          // dead after gemm_qkv -> Op alias
    ushort* Cb  = (ushort*)(w8 + 8388608);
    ushort* Qb  = (ushort*)(w8 + 16777216);
    ushort* KV  = (ushort*)(w8 + 25165824);   // [4096][2048] bf16 = 16 MB
    ushort* Wqt = (ushort*)(w8 + 50331648);   // dead after gemm_qkv -> ml alias
    ushort* Wkt = (ushort*)(w8 + 52428800);   // [WkT;WvT] fused 2048x1024
    ushort* Wvt = (ushort*)(w8 + 54525952);
    ushort* Wot = (ushort*)(w8 + 56623104);
    int*    clsp = (int*)(w8 + 58720256);
    ushort* Op   = Pb;                        // 2 x 8.4 MB partials (Pb+Cb)
    float2* mlp  = (float2*)Wqt;              // 1 MB

    prep<<<11264, 256, 0, stream>>>(primary, context, Pb, Cb,
                                    Wq, Wk, Wv, Wo, Wqt, Wkt, Wvt, Wot,
                                    amask, pmask, clsp);
    gemm_qkv<<<dim3(24, 32), 256, 0, stream>>>(Pb, Cb, Wqt, Wkt, Qb, KV);
    attn_mfma<<<dim3(16, 16, 4), 256, 0, stream>>>(Qb, KV, amask, pmask, clsp, Op, mlp);
    gemm_out_fused<<<dim3(8, 64), 256, 0, stream>>>(Op, mlp, Wot, bo, out);
}